// Round 8
// baseline (674.554 us; speedup 1.0000x reference)
//
#include <hip/hip_runtime.h>

#define EPS 0.001f

typedef __attribute__((ext_vector_type(8))) short bf16x8;
typedef __attribute__((ext_vector_type(4))) float f32x4;

// ---- problem sizes ----
constexpr int Bn = 8, Tx = 20, Dx = 24, Hx = 24, Wx = 24;
constexpr int Cmid = 12, CoutN = 36;
constexpr int T1 = 18, D1 = 22;
constexpr int T2 = 16, D2 = 20;

// x strides (fp32)
constexpr int SXD = 576, SXT = 13824, SXC = 276480;
constexpr long SXB = 1105920;

// h1t: [b][t18][d22][h22][w22][c16] bf16
constexpr int HTW = 16;
constexpr int HTH = 22 * 16;          // 352
constexpr int HTD = 22 * 22 * 16;     // 7744
constexpr int HTT = 22 * HTD;         // 170368
constexpr long HTB = (long)T1 * HTT;  // 3066624

// out strides (fp32)
constexpr int S2D = 400, S2T = 8000, S2O = 128000;
constexpr long S2B = 4608000;

constexpr int NBLK1 = 8 * 18 * 11;    // 1584 conv1 blocks

__device__ __forceinline__ unsigned short f2bf(float f) {
    unsigned u = __builtin_bit_cast(unsigned, f);
    u = (u + 0x7fffu + ((u >> 16) & 1u)) >> 16;
    return (unsigned short)u;
}

// Transpose W1 [o][cin][kt][kd][kh][kw] -> W1t [cin*81 + tap][o] (o contiguous)
__global__ void k_w1t(const float* __restrict__ W1, float* __restrict__ W1t) {
    int i = blockIdx.x * 256 + threadIdx.x;
    if (i < Cmid * 4 * 81) {
        int o = i / 324;
        int r = i - o * 324;
        W1t[r * Cmid + o] = W1[i];
    }
}

// conv1 + relu; writes h1t (bf16 channel-last, c padded to 16) and
// deterministic per-block stats partials part[bid*24 + {c:sum, 12+c:sumsq}]
__global__ __launch_bounds__(1024) void k_conv1(
    const float* __restrict__ x, const float* __restrict__ W1t,
    const float* __restrict__ b1, unsigned short* __restrict__ h1t,
    float* __restrict__ part)
{
    __shared__ float st[4 * 576];
    __shared__ float ssum[16][12], ssq[16][12];

    const int tid = threadIdx.x;
    const int dp = blockIdx.x;          // 0..10 -> d0 = 2*dp
    const int t  = blockIdx.y;          // 0..17
    const int b  = blockIdx.z;          // 0..7
    const int d0 = dp * 2;
    const int bid = (b * 18 + t) * 11 + dp;

    const bool active = tid < 968;
    int dd = 0, h = 0, w = 0;
    if (active) { dd = tid / 484; int r = tid - dd * 484; h = r / 22; w = r - h * 22; }

    float acc[12];
#pragma unroll
    for (int c = 0; c < 12; ++c) acc[c] = 0.f;

    const int lbase = dd * 576 + h * 24 + w;

    for (int cin = 0; cin < 4; ++cin) {
        for (int kt = 0; kt < 3; ++kt) {
            __syncthreads();
            const float* src = x + (long)b * SXB + (long)cin * SXC
                             + (long)(t + kt) * SXT + (long)d0 * SXD;
            for (int s = tid; s < 2304; s += 1024) st[s] = src[s];
            __syncthreads();
            if (active) {
                const float* wp = W1t + (cin * 81 + kt * 27) * 12;
#pragma unroll
                for (int kd = 0; kd < 3; ++kd)
#pragma unroll
                for (int kh = 0; kh < 3; ++kh)
#pragma unroll
                for (int kw = 0; kw < 3; ++kw) {
                    float xv = st[lbase + kd * 576 + kh * 24 + kw];
                    const float* wq = wp + (kd * 9 + kh * 3 + kw) * 12;
#pragma unroll
                    for (int c = 0; c < 12; ++c) acc[c] = fmaf(wq[c], xv, acc[c]);
                }
            }
        }
    }

    float v[12];
#pragma unroll
    for (int c = 0; c < 12; ++c)
        v[c] = active ? fmaxf(acc[c] + b1[c], 0.f) : 0.f;

    const int lane = tid & 63;
    const int wv   = tid >> 6;
#pragma unroll
    for (int c = 0; c < 12; ++c) {
        float s = v[c], q = v[c] * v[c];
#pragma unroll
        for (int off = 32; off > 0; off >>= 1) {
            s += __shfl_down(s, off);
            q += __shfl_down(q, off);
        }
        if (lane == 0) { ssum[wv][c] = s; ssq[wv][c] = q; }
    }

    if (active) {
        const long tb = (long)b * HTB + (long)t * HTT + (long)(d0 + dd) * HTD
                      + (long)h * HTH + (long)w * HTW;
        uint4 p0, p1;
        p0.x = (unsigned)f2bf(v[0]) | ((unsigned)f2bf(v[1]) << 16);
        p0.y = (unsigned)f2bf(v[2]) | ((unsigned)f2bf(v[3]) << 16);
        p0.z = (unsigned)f2bf(v[4]) | ((unsigned)f2bf(v[5]) << 16);
        p0.w = (unsigned)f2bf(v[6]) | ((unsigned)f2bf(v[7]) << 16);
        p1.x = (unsigned)f2bf(v[8]) | ((unsigned)f2bf(v[9]) << 16);
        p1.y = (unsigned)f2bf(v[10]) | ((unsigned)f2bf(v[11]) << 16);
        p1.z = 0u; p1.w = 0u;
        *(uint4*)(h1t + tb) = p0;
        *(uint4*)(h1t + tb + 8) = p1;
    }

    __syncthreads();
    // deterministic in-block reduction of 16 wave partials
    if (tid < 12) {
        float s = 0.f;
#pragma unroll
        for (int i = 0; i < 16; ++i) s += ssum[i][tid];
        part[bid * 24 + tid] = s;
    } else if (tid < 24) {
        float s = 0.f;
#pragma unroll
        for (int i = 0; i < 16; ++i) s += ssq[i][tid - 12];
        part[bid * 24 + tid] = s;
    }
}

// deterministic cross-block reduction: 24 blocks, one per stat channel
__global__ void k_red(const float* __restrict__ part, float* __restrict__ stats2) {
    __shared__ float s[256];
    const int c = blockIdx.x;      // 0..23
    const int tid = threadIdx.x;   // 0..255
    float acc = 0.f;
    for (int i = tid; i < NBLK1; i += 256) acc += part[i * 24 + c];
    s[tid] = acc;
    __syncthreads();
    for (int off = 128; off > 0; off >>= 1) {
        if (tid < off) s[tid] += s[tid + off];
        __syncthreads();
    }
    if (tid == 0) stats2[c] = s[0];
}

// finalize BN (parallel): block o computes b2ws[o]; block 0 also writes abuf.
__global__ void k_fin1(const float* __restrict__ stats2, const float* __restrict__ gamma,
                       const float* __restrict__ beta, const float* __restrict__ W2,
                       const float* __restrict__ b2, float* __restrict__ abuf,
                       float* __restrict__ b2ws)
{
    __shared__ float d_sh[12];
    const int o = blockIdx.x;        // 0..35
    const int lane = threadIdx.x;    // 0..63
    if (lane < 12) {
        const float N = 1533312.f;   // 8*18*22*22*22
        float mean = stats2[lane] / N;
        float var  = stats2[12 + lane] / N - mean * mean;
        float a = gamma[lane] * rsqrtf(var + EPS);
        if (o == 0) abuf[lane] = a;
        d_sh[lane] = beta[lane] - mean * a;
    }
    __syncthreads();
    float s = 0.f;
    for (int j = lane; j < 972; j += 64) {
        int c = j / 81;
        s += W2[o * 972 + j] * d_sh[c];
    }
#pragma unroll
    for (int off = 32; off > 0; off >>= 1) s += __shfl_down(s, off);
    if (lane == 0) b2ws[o] = b2[o] + s;
}

// Build conv2 A-operand fragment-ordered weights Wf (BN-scaled).
__global__ void k_fin2(const float* __restrict__ W2, const float* __restrict__ abuf,
                       unsigned short* __restrict__ Wf)
{
    const int bi = blockIdx.x;       // 0..161
    const int lane = threadIdx.x;    // 0..63
    const int ch = bi & 1;
    const int tmp = bi >> 1;
    const int mt = tmp % 3;
    const int g = tmp / 3;
    const int kt = g / 9, g9 = g % 9, kd = g9 / 3, kh = g9 % 3;
    const int o = mt * 16 + (lane & 15);

    unsigned short vals[8];
#pragma unroll
    for (int j = 0; j < 8; ++j) {
        int k = ch * 32 + ((lane >> 4) << 3) + j;
        float v = 0.f;
        if (k < 48 && o < 36) {
            int kw = k >> 4, c = k & 15;
            if (c < 12)
                v = W2[o * 972 + c * 81 + kt * 27 + kd * 9 + kh * 3 + kw] * abuf[c];
        }
        vals[j] = f2bf(v);
    }
    uint4 pk;
    pk.x = (unsigned)vals[0] | ((unsigned)vals[1] << 16);
    pk.y = (unsigned)vals[2] | ((unsigned)vals[3] << 16);
    pk.z = (unsigned)vals[4] | ((unsigned)vals[5] << 16);
    pk.w = (unsigned)vals[6] | ((unsigned)vals[7] << 16);
    *(uint4*)(Wf + bi * 512 + lane * 8) = pk;
}

// MFMA implicit-GEMM conv2. Block = (d, t, b) output plane (20x20 = 25 pos-tiles).
// LDS: 3 input d-planes, layout per plane: 16B unit index = h*44 + chalf*22 + w.
__global__ __launch_bounds__(320, 3) void k_conv2m(
    const unsigned short* __restrict__ h1t, const unsigned short* __restrict__ Wf,
    const float* __restrict__ b2ws, float* __restrict__ out)
{
    __shared__ char lds[3 * 15488];

    const int tid  = threadIdx.x;
    const int lane = tid & 63;
    const int wv   = tid >> 6;     // 0..4
    const int d = blockIdx.x;      // 0..19
    const int t = blockIdx.y;      // 0..15
    const int b = blockIdx.z;      // 0..7

    const int n16 = lane & 15;
    const int q   = lane >> 4;

    int posbase[5], pb[5];
#pragma unroll
    for (int u = 0; u < 5; ++u) {
        int p = (wv * 5 + u) * 16 + n16;
        int h = p / 20, w = p - h * 20;
        pb[u] = p;
        posbase[u] = h * 704 + w * 16;
    }
    const int qoff0 = (q & 1) * 352 + (q >> 1) * 16;
    const int qoff1 = (q & 1) * 352 + 32;

    f32x4 acc[5][3];
#pragma unroll
    for (int u = 0; u < 5; ++u)
#pragma unroll
        for (int mt = 0; mt < 3; ++mt)
            acc[u][mt] = (f32x4){0.f, 0.f, 0.f, 0.f};

    for (int kt = 0; kt < 3; ++kt) {
        __syncthreads();
        {
            // h1t[b, t+kt, d..d+2] contiguous: permuted copy into [pl][h][chalf][w]
            const unsigned short* src = h1t + (long)b * HTB + (long)(t + kt) * HTT
                                      + (long)d * HTD;
            for (int i = tid; i < 2904; i += 320) {
                int pl = i / 968; int r = i - pl * 968;
                int h = r / 44; int r2 = r - h * 44;
                int w = r2 >> 1, chh = r2 & 1;
                int dst = pl * 968 + h * 44 + chh * 22 + w;
                *(uint4*)(lds + dst * 16) = *(const uint4*)(src + i * 8);
            }
        }
        __syncthreads();

#pragma unroll
        for (int g9 = 0; g9 < 9; ++g9) {
            const int kd = g9 / 3, kh = g9 - kd * 3;
            const int g = kt * 9 + g9;

            bf16x8 A[3][2];
#pragma unroll
            for (int mt = 0; mt < 3; ++mt)
#pragma unroll
                for (int c2 = 0; c2 < 2; ++c2)
                    A[mt][c2] = *(const bf16x8*)(Wf + (((g * 3 + mt) * 2 + c2) << 9) + lane * 8);

            const int goff = kd * 15488 + kh * 704;
#pragma unroll
            for (int u = 0; u < 5; ++u) {
                bf16x8 b0 = *(const bf16x8*)(lds + posbase[u] + goff + qoff0);
                bf16x8 b1 = *(const bf16x8*)(lds + posbase[u] + goff + qoff1);
#pragma unroll
                for (int mt = 0; mt < 3; ++mt) {
                    acc[u][mt] = __builtin_amdgcn_mfma_f32_16x16x32_bf16(A[mt][0], b0, acc[u][mt], 0, 0, 0);
                    acc[u][mt] = __builtin_amdgcn_mfma_f32_16x16x32_bf16(A[mt][1], b1, acc[u][mt], 0, 0, 0);
                }
            }
        }
    }

    const long ob = (long)b * S2B + (long)t * S2T + (long)d * S2D;
#pragma unroll
    for (int mt = 0; mt < 3; ++mt)
#pragma unroll
    for (int r = 0; r < 4; ++r) {
        const int o = mt * 16 + q * 4 + r;
        if (o < 36) {
            const float bias = b2ws[o];
#pragma unroll
            for (int u = 0; u < 5; ++u)
                out[ob + (long)o * S2O + pb[u]] = fmaxf(acc[u][mt][r] + bias, 0.f);
        }
    }
}

extern "C" void kernel_launch(void* const* d_in, const int* in_sizes, int n_in,
                              void* d_out, int out_size, void* d_ws, size_t ws_size,
                              hipStream_t stream) {
    const float* x     = (const float*)d_in[0];
    const float* W1    = (const float*)d_in[1];
    const float* b1    = (const float*)d_in[2];
    const float* gamma = (const float*)d_in[3];
    const float* beta  = (const float*)d_in[4];
    const float* W2    = (const float*)d_in[5];
    const float* b2    = (const float*)d_in[6];
    float* out = (float*)d_out;

    float* ws     = (float*)d_ws;
    float* stats2 = ws;                                  // 24 f
    float* abuf   = ws + 32;                             // 12 f
    float* b2ws   = ws + 64;                             // 36 f
    float* W1t    = ws + 128;                            // 3888 f
    unsigned short* Wf  = (unsigned short*)((char*)d_ws + 16384);   // 165888 B
    float* part   = (float*)((char*)d_ws + 196608);      // 1584*24 f
    unsigned short* h1t = (unsigned short*)((char*)d_ws + 524288);  // 49.07 MB

    k_w1t<<<16, 256, 0, stream>>>(W1, W1t);
    k_conv1<<<dim3(11, 18, 8), 1024, 0, stream>>>(x, W1t, b1, h1t, part);
    k_red<<<24, 256, 0, stream>>>(part, stats2);
    k_fin1<<<36, 64, 0, stream>>>(stats2, gamma, beta, W2, b2, abuf, b2ws);
    k_fin2<<<162, 64, 0, stream>>>(W2, abuf, Wf);
    k_conv2m<<<dim3(20, 16, 8), 320, 0, stream>>>(h1t, Wf, b2ws, out);
}